// Round 1
// baseline (4123.842 us; speedup 1.0000x reference)
//
#include <hip/hip_runtime.h>

// Problem: B=32, C=64, H=W=112, per-sample 3x3 convs (hypernetwork weights),
// BN (train-mode batch stats, biased var, eps=1e-5), ReLU, residual.
#define HW   112
#define HW2  (HW*HW)          // 12544
#define CH   64
#define NB   32
#define TS   16               // spatial tile
#define CCH  32               // cin chunk staged in LDS
#define NPC  (NB*HW2)         // per-channel element count: 401408

using u16 = unsigned short;

__device__ __forceinline__ float b2f(u16 u) {
    union { unsigned int i; float f; } c;
    c.i = ((unsigned int)u) << 16;
    return c.f;
}
__device__ __forceinline__ u16 f2b(float f) {
    union { float f; unsigned int i; } c;
    c.f = f;
    unsigned int x = c.i;
    x += 0x7fffu + ((x >> 16) & 1u);   // round-to-nearest-even
    return (u16)(x >> 16);
}

// MODE 0: input = raw f32 x (conv1).  MODE 1: input = bf16 out1 with
// folded BN1 affine + ReLU applied during LDS staging (conv2).
template<int MODE>
__global__ __launch_bounds__(256)
void conv3x3_kernel(const float* __restrict__ xf,
                    const u16*   __restrict__ xb,
                    const float* __restrict__ w,      // [B][64][64][3][3]
                    const float* __restrict__ scale,  // [64] (MODE 1)
                    const float* __restrict__ bias,   // [64] (MODE 1)
                    u16*         __restrict__ out)    // [B][64][112][112] bf16
{
    __shared__ float xt[CCH][18][18];
    const int b   = blockIdx.z;
    const int ty0 = blockIdx.y * TS, tx0 = blockIdx.x * TS;
    const int tid = threadIdx.x;
    const int px  = tid & 15, py = tid >> 4;

    float acc[CH];
#pragma unroll
    for (int i = 0; i < CH; ++i) acc[i] = 0.f;

    const float*  wb    = w + (size_t)b * CH * CH * 9;   // block-uniform -> s_load
    const size_t  xbase = (size_t)b * CH * HW2;

    for (int cc = 0; cc < CH; cc += CCH) {
        // ---- stage input tile (with halo) into LDS ----
        for (int idx = tid; idx < CCH * 18 * 18; idx += 256) {
            int ci = idx / 324;
            int r  = idx - ci * 324;
            int iy = r / 18;
            int ix = r - iy * 18;
            int gy = ty0 + iy - 1, gx = tx0 + ix - 1;
            float v = 0.f;
            if ((unsigned)gy < HW && (unsigned)gx < HW) {
                size_t g = xbase + (size_t)(cc + ci) * HW2 + (size_t)gy * HW + gx;
                if (MODE == 0) {
                    v = xf[g];
                } else {
                    float t = b2f(xb[g]);
                    t = t * scale[cc + ci] + bias[cc + ci];
                    v = t > 0.f ? t : 0.f;
                }
            }
            xt[ci][iy][ix] = v;
        }
        __syncthreads();

        // ---- compute: 1 pixel x 64 couts per thread ----
#pragma unroll 1
        for (int ci = 0; ci < CCH; ++ci) {
            float xv[9];
#pragma unroll
            for (int dy = 0; dy < 3; ++dy)
#pragma unroll
                for (int dx = 0; dx < 3; ++dx)
                    xv[dy * 3 + dx] = xt[ci][py + dy][px + dx];
            const float* wc = wb + (cc + ci) * 9;
#pragma unroll
            for (int co = 0; co < CH; ++co) {
                const float* wcc = wc + co * (CH * 9);   // uniform -> scalar loads
                float a = acc[co];
#pragma unroll
                for (int t = 0; t < 9; ++t) a = fmaf(xv[t], wcc[t], a);
                acc[co] = a;
            }
        }
        __syncthreads();
    }

    const int oy = ty0 + py, ox = tx0 + px;
    const size_t obase = xbase + (size_t)oy * HW + ox;
#pragma unroll
    for (int co = 0; co < CH; ++co)
        out[obase + (size_t)co * HW2] = f2b(acc[co]);
}

// Per-(b,c) partial sums of y and y^2, atomically accumulated per channel.
__global__ __launch_bounds__(256)
void stats_kernel(const u16* __restrict__ y, float* __restrict__ sums) // sums: [sum(64), sumsq(64)]
{
    const int blk = blockIdx.x;          // b*64 + c
    const int c   = blk & 63;
    const u16* p  = y + (size_t)blk * HW2;
    float s = 0.f, q = 0.f;
    for (int i = threadIdx.x; i < HW2 / 4; i += 256) {
        ushort4 v = reinterpret_cast<const ushort4*>(p)[i];
        float a0 = b2f(v.x), a1 = b2f(v.y), a2 = b2f(v.z), a3 = b2f(v.w);
        s += (a0 + a1) + (a2 + a3);
        q += (a0 * a0 + a1 * a1) + (a2 * a2 + a3 * a3);
    }
#pragma unroll
    for (int off = 32; off > 0; off >>= 1) {
        s += __shfl_xor(s, off);
        q += __shfl_xor(q, off);
    }
    __shared__ float ls[8];
    int wave = threadIdx.x >> 6;
    int lane = threadIdx.x & 63;
    if (lane == 0) { ls[wave] = s; ls[4 + wave] = q; }
    __syncthreads();
    if (threadIdx.x == 0) {
        atomicAdd(&sums[c],      ls[0] + ls[1] + ls[2] + ls[3]);
        atomicAdd(&sums[64 + c], ls[4] + ls[5] + ls[6] + ls[7]);
    }
}

__global__ void bnparam_kernel(const float* __restrict__ sums,
                               const float* __restrict__ gamma,
                               const float* __restrict__ beta,
                               float* __restrict__ sb)   // [scale(64), bias(64)]
{
    int c = threadIdx.x;
    if (c < 64) {
        float mean = sums[c] * (1.f / NPC);
        float var  = sums[64 + c] * (1.f / NPC) - mean * mean;
        float s    = gamma[c] * rsqrtf(var + 1e-5f);
        sb[c]      = s;
        sb[64 + c] = beta[c] - mean * s;
    }
}

__global__ void zero_kernel(float* __restrict__ p, int n)
{
    int i = blockIdx.x * 256 + threadIdx.x;
    if (i < n) p[i] = 0.f;
}

// out = relu(bn2(out2) + x), f32 output
__global__ __launch_bounds__(256)
void finalize_kernel(const u16* __restrict__ y2, const float* __restrict__ x,
                     const float* __restrict__ sb, float* __restrict__ out)
{
    unsigned int i = (blockIdx.x * 256u + threadIdx.x) * 4u;
    unsigned int c = (i / HW2) & 63u;     // 4 consecutive elems share channel
    float s = sb[c], b = sb[64 + c];
    ushort4 v = *reinterpret_cast<const ushort4*>(y2 + i);
    float4 xv = *reinterpret_cast<const float4*>(x + i);
    float4 r;
    r.x = fmaxf(fmaf(b2f(v.x), s, b) + xv.x, 0.f);
    r.y = fmaxf(fmaf(b2f(v.y), s, b) + xv.y, 0.f);
    r.z = fmaxf(fmaf(b2f(v.z), s, b) + xv.z, 0.f);
    r.w = fmaxf(fmaf(b2f(v.w), s, b) + xv.w, 0.f);
    *reinterpret_cast<float4*>(out + i) = r;
}

extern "C" void kernel_launch(void* const* d_in, const int* in_sizes, int n_in,
                              void* d_out, int out_size, void* d_ws, size_t ws_size,
                              hipStream_t stream)
{
    const float* x  = (const float*)d_in[0];
    const float* w1 = (const float*)d_in[1];
    const float* w2 = (const float*)d_in[2];
    const float* g1 = (const float*)d_in[3];
    const float* b1 = (const float*)d_in[4];
    const float* g2 = (const float*)d_in[5];
    const float* b2 = (const float*)d_in[6];
    float* out = (float*)d_out;

    char* ws = (char*)d_ws;
    const size_t nElem = (size_t)NB * CH * HW2;        // 25,690,112
    u16*   out1 = (u16*)ws;                            // bf16 intermediate 1
    u16*   out2 = (u16*)(ws + nElem * 2);              // bf16 intermediate 2
    float* st   = (float*)(ws + nElem * 4);            // stats area
    float* sums1 = st;            // 128 floats
    float* sums2 = st + 128;      // 128 floats
    float* sb1   = st + 256;      // scale1/bias1
    float* sb2   = st + 384;      // scale2/bias2

    zero_kernel<<<1, 256, 0, stream>>>(st, 256);

    dim3 cgrid(HW / TS, HW / TS, NB);   // 7 x 7 x 32
    conv3x3_kernel<0><<<cgrid, 256, 0, stream>>>(x, nullptr, w1, nullptr, nullptr, out1);
    stats_kernel<<<NB * CH, 256, 0, stream>>>(out1, sums1);
    bnparam_kernel<<<1, 64, 0, stream>>>(sums1, g1, b1, sb1);
    conv3x3_kernel<1><<<cgrid, 256, 0, stream>>>(nullptr, out1, w2, sb1, sb1 + 64, out2);
    stats_kernel<<<NB * CH, 256, 0, stream>>>(out2, sums2);
    bnparam_kernel<<<1, 64, 0, stream>>>(sums2, g2, b2, sb2);
    finalize_kernel<<<(unsigned)(nElem / 4 / 256), 256, 0, stream>>>(out2, x, sb2, out);
}

// Round 2
// 332.665 us; speedup vs baseline: 12.3964x; 12.3964x over previous
//
#include <hip/hip_runtime.h>

// B=32, C=64, H=W=112. Per-sample 3x3 convs via bf16 MFMA implicit GEMM.
// Per sample GEMM: M=64 (cout), K=576 (cin*9), N=12544 (pixels).
#define HW   112
#define HW2  12544
#define CH   64
#define NB   32
#define TS   16
#define HP   18
#define NPIX 324            // 18*18
#define NPC  (NB*HW2)       // per-channel count for BN stats

using u16 = unsigned short;
typedef __attribute__((ext_vector_type(8))) short bf16x8;   // 8 bf16 = 4 VGPRs
typedef __attribute__((ext_vector_type(4))) float f32x4;

__device__ __forceinline__ float b2f(u16 u) {
    union { unsigned int i; float f; } c;
    c.i = ((unsigned int)u) << 16;
    return c.f;
}
__device__ __forceinline__ u16 f2b(float f) {
    union { float f; unsigned int i; } c;
    c.f = f;
    unsigned int x = c.i;
    x += 0x7fffu + ((x >> 16) & 1u);   // RNE
    return (u16)(x >> 16);
}

// LDS tile: [pix 0..323][ci 0..63] bf16, 128 B per pixel row.
// XOR-swizzle byte bits 4-6 with pix&7: conflict-free ds_read_b128/ds_write_b128.
__device__ __forceinline__ int swz(int pix, int ci) {
    return (pix * 128 + ci * 2) ^ ((pix & 7) << 4);
}

// MODE 0: input = raw f32 x [b][ci][y][x]   (conv1)
// MODE 1: input = bf16 out1 [b][y][x][ci] with BN1 affine + ReLU fused (conv2)
// wt: bf16 [b][tap][co][ci]. out: bf16 [b][y][x][co]. sums: 128 floats (sum, sumsq).
template<int MODE>
__global__ __launch_bounds__(256)
void conv_mfma(const float* __restrict__ xf, const u16* __restrict__ xb,
               const u16* __restrict__ wt, const float* __restrict__ sbp,
               u16* __restrict__ out, float* __restrict__ sums)
{
    __shared__ u16 xt[NPIX * CH];
    const int b   = blockIdx.z;
    const int ty0 = blockIdx.y * TS, tx0 = blockIdx.x * TS;
    const int tid = threadIdx.x;

    // ---- stage 18x18x64 input tile into LDS (pixel-major, swizzled) ----
    for (int task = tid; task < NPIX * 8; task += 256) {
        int g  = task / NPIX;            // ci group (8 ci)
        int r  = task - g * NPIX;        // pixel index in tile
        int iy = r / HP, ix = r - iy * HP;
        int gy = ty0 + iy - 1, gx = tx0 + ix - 1;
        bool ok = ((unsigned)gy < HW) && ((unsigned)gx < HW);
        bf16x8 pk = (bf16x8)0;
        if (MODE == 0) {
            if (ok) {
                const float* src = xf + ((size_t)b * CH + g * 8) * HW2 + gy * HW + gx;
#pragma unroll
                for (int j = 0; j < 8; ++j)
                    pk[j] = (short)f2b(src[(size_t)j * HW2]);
            }
        } else {
            if (ok) {
                const u16* src = xb + ((size_t)b * HW2 + gy * HW + gx) * CH + g * 8;
                bf16x8 v = *(const bf16x8*)src;
                float4 s0 = *(const float4*)(sbp + g * 8);
                float4 s1 = *(const float4*)(sbp + g * 8 + 4);
                float4 c0 = *(const float4*)(sbp + 64 + g * 8);
                float4 c1 = *(const float4*)(sbp + 64 + g * 8 + 4);
                float sc[8] = {s0.x, s0.y, s0.z, s0.w, s1.x, s1.y, s1.z, s1.w};
                float bi[8] = {c0.x, c0.y, c0.z, c0.w, c1.x, c1.y, c1.z, c1.w};
#pragma unroll
                for (int j = 0; j < 8; ++j) {
                    float t = b2f((u16)v[j]) * sc[j] + bi[j];
                    pk[j] = (short)f2b(t > 0.f ? t : 0.f);
                }
            }
        }
        *(bf16x8*)((char*)xt + swz(r, g * 8)) = pk;
    }
    __syncthreads();

    // ---- MFMA main loop: wave handles 4 pixel-rows x all 64 couts ----
    const int lane = tid & 63, wave = tid >> 6;
    const int px = lane & 15, kg = lane >> 4;
    const int y0 = wave * 4;
    const u16* wtb = wt + (size_t)b * 9 * CH * CH;

    f32x4 acc[4][4];
#pragma unroll
    for (int r = 0; r < 4; ++r)
#pragma unroll
        for (int m = 0; m < 4; ++m) acc[r][m] = (f32x4)0.f;

#pragma unroll
    for (int dy = 0; dy < 3; ++dy)
#pragma unroll
    for (int dx = 0; dx < 3; ++dx)
#pragma unroll
    for (int kc = 0; kc < 2; ++kc) {
        const int ci0 = kc * 32 + kg * 8;
        const u16* wp = wtb + (size_t)(dy * 3 + dx) * CH * CH + ci0;
        bf16x8 af[4];
#pragma unroll
        for (int m = 0; m < 4; ++m)
            af[m] = *(const bf16x8*)(wp + (m * 16 + px) * CH);   // A: row=lane&15=co
#pragma unroll
        for (int r = 0; r < 4; ++r) {
            int pr = (y0 + r + dy) * HP + (px + dx);
            bf16x8 bfr = *(const bf16x8*)((const char*)xt + swz(pr, ci0)); // B: col=px
#pragma unroll
            for (int m = 0; m < 4; ++m)
                acc[r][m] = __builtin_amdgcn_mfma_f32_16x16x32_bf16(af[m], bfr, acc[r][m], 0, 0, 0);
        }
    }

    // ---- epilogue: bf16 store [b][y][x][co] + fused BN batch-stat partials ----
    float s[4][4], ss[4][4];
#pragma unroll
    for (int m = 0; m < 4; ++m)
#pragma unroll
        for (int q = 0; q < 4; ++q) { s[m][q] = 0.f; ss[m][q] = 0.f; }

    const size_t obase = ((size_t)b * HW2 + (size_t)(ty0 + y0) * HW + tx0 + px) * CH + kg * 4;
#pragma unroll
    for (int r = 0; r < 4; ++r) {
#pragma unroll
        for (int m = 0; m < 4; ++m) {
            float v0 = acc[r][m][0], v1 = acc[r][m][1], v2 = acc[r][m][2], v3 = acc[r][m][3];
            s[m][0] += v0; s[m][1] += v1; s[m][2] += v2; s[m][3] += v3;
            ss[m][0] += v0 * v0; ss[m][1] += v1 * v1; ss[m][2] += v2 * v2; ss[m][3] += v3 * v3;
            uint2 pk;
            pk.x = ((unsigned)f2b(v1) << 16) | f2b(v0);
            pk.y = ((unsigned)f2b(v3) << 16) | f2b(v2);
            *(uint2*)(out + obase + (size_t)r * HW * CH + m * 16) = pk;
        }
    }
    // reduce partials across the 16 px lanes (channels owned per (kg,m,q))
#pragma unroll
    for (int off = 1; off < 16; off <<= 1) {
#pragma unroll
        for (int m = 0; m < 4; ++m)
#pragma unroll
            for (int q = 0; q < 4; ++q) {
                s[m][q]  += __shfl_xor(s[m][q], off);
                ss[m][q] += __shfl_xor(ss[m][q], off);
            }
    }
    __syncthreads();                    // done reading xt; reuse as reduce buffer
    float* red = (float*)xt;
    if (px == 0) {
#pragma unroll
        for (int m = 0; m < 4; ++m)
#pragma unroll
            for (int q = 0; q < 4; ++q) {
                int c = m * 16 + kg * 4 + q;
                red[wave * 128 + c]      = s[m][q];
                red[wave * 128 + 64 + c] = ss[m][q];
            }
    }
    __syncthreads();
    if (tid < 128) {
        float t = red[tid] + red[128 + tid] + red[256 + tid] + red[384 + tid];
        atomicAdd(&sums[tid], t);
    }
}

// w [b][co][ci][3][3] f32  ->  wt [b][tap][co][ci] bf16
__global__ __launch_bounds__(256)
void repack_kernel(const float* __restrict__ w, u16* __restrict__ wt)
{
    int i  = blockIdx.x * 256 + threadIdx.x;   // 32*9*64*64 = 1179648 exact
    int ci = i & 63;
    int co = (i >> 6) & 63;
    int bt = i >> 12;                          // b*9 + t
    int t  = bt % 9;
    int b  = bt / 9;
    wt[i] = f2b(w[(((size_t)b * 64 + co) * 64 + ci) * 9 + t]);
}

__global__ void bnparam_kernel(const float* __restrict__ sums,
                               const float* __restrict__ gamma,
                               const float* __restrict__ beta,
                               float* __restrict__ sb)
{
    int c = threadIdx.x;
    if (c < 64) {
        float mean = sums[c] * (1.f / NPC);
        float var  = sums[64 + c] * (1.f / NPC) - mean * mean;
        float sc   = gamma[c] * rsqrtf(var + 1e-5f);
        sb[c]      = sc;
        sb[64 + c] = beta[c] - mean * sc;
    }
}

__global__ void zero_kernel(float* __restrict__ p, int n)
{
    int i = blockIdx.x * 256 + threadIdx.x;
    if (i < n) p[i] = 0.f;
}

// out = relu(bn2(y2) + x); y2 [b][pix][c] bf16, x/out [b][c][pix] f32 (LDS transpose)
__global__ __launch_bounds__(256)
void finalize_kernel(const u16* __restrict__ y2, const float* __restrict__ x,
                     const float* __restrict__ sb, float* __restrict__ out)
{
    __shared__ float lt[64][33];
    const int b  = blockIdx.y;
    const int p0 = blockIdx.x * 32;
    const int t  = threadIdx.x;
    {
        int pi = t >> 3, cg = (t & 7) * 8;
        const u16* src = y2 + ((size_t)b * HW2 + p0 + pi) * CH + cg;
        bf16x8 v = *(const bf16x8*)src;
        float4 s0 = *(const float4*)(sb + cg);
        float4 s1 = *(const float4*)(sb + cg + 4);
        float4 c0 = *(const float4*)(sb + 64 + cg);
        float4 c1 = *(const float4*)(sb + 64 + cg + 4);
        float sc[8] = {s0.x, s0.y, s0.z, s0.w, s1.x, s1.y, s1.z, s1.w};
        float bi[8] = {c0.x, c0.y, c0.z, c0.w, c1.x, c1.y, c1.z, c1.w};
#pragma unroll
        for (int j = 0; j < 8; ++j)
            lt[cg + j][pi] = b2f((u16)v[j]) * sc[j] + bi[j];
    }
    __syncthreads();
    {
        int c = t >> 2, xg = (t & 3) * 8;
        size_t base = ((size_t)b * CH + c) * HW2 + p0 + xg;
        float4 x0 = *(const float4*)(x + base);
        float4 x1 = *(const float4*)(x + base + 4);
        float4 r0, r1;
        r0.x = fmaxf(lt[c][xg + 0] + x0.x, 0.f);
        r0.y = fmaxf(lt[c][xg + 1] + x0.y, 0.f);
        r0.z = fmaxf(lt[c][xg + 2] + x0.z, 0.f);
        r0.w = fmaxf(lt[c][xg + 3] + x0.w, 0.f);
        r1.x = fmaxf(lt[c][xg + 4] + x1.x, 0.f);
        r1.y = fmaxf(lt[c][xg + 5] + x1.y, 0.f);
        r1.z = fmaxf(lt[c][xg + 6] + x1.z, 0.f);
        r1.w = fmaxf(lt[c][xg + 7] + x1.w, 0.f);
        *(float4*)(out + base)     = r0;
        *(float4*)(out + base + 4) = r1;
    }
}

extern "C" void kernel_launch(void* const* d_in, const int* in_sizes, int n_in,
                              void* d_out, int out_size, void* d_ws, size_t ws_size,
                              hipStream_t stream)
{
    const float* x  = (const float*)d_in[0];
    const float* w1 = (const float*)d_in[1];
    const float* w2 = (const float*)d_in[2];
    const float* g1 = (const float*)d_in[3];
    const float* b1 = (const float*)d_in[4];
    const float* g2 = (const float*)d_in[5];
    const float* b2 = (const float*)d_in[6];
    float* out = (float*)d_out;

    char* ws = (char*)d_ws;
    const size_t nElem = (size_t)NB * CH * HW2;        // 25,690,112
    u16*   out1  = (u16*)ws;                           // [0, 51.38 MB)
    u16*   out2  = (u16*)(ws + nElem * 2);             // [51.38, 102.76 MB)
    float* st    = (float*)(ws + nElem * 4);           // 512 floats
    float* sums1 = st, *sums2 = st + 128, *sb1 = st + 256, *sb2 = st + 384;
    u16*   wt1   = out2;                               // dead until conv2 writes out2
    u16*   wt2   = (u16*)d_out;                        // dead until finalize writes out

    zero_kernel<<<1, 256, 0, stream>>>(st, 256);
    repack_kernel<<<4608, 256, 0, stream>>>(w1, wt1);

    dim3 cgrid(HW / TS, HW / TS, NB);                  // 7 x 7 x 32
    conv_mfma<0><<<cgrid, 256, 0, stream>>>(x, nullptr, wt1, nullptr, out1, sums1);
    bnparam_kernel<<<1, 64, 0, stream>>>(sums1, g1, b1, sb1);

    repack_kernel<<<4608, 256, 0, stream>>>(w2, wt2);
    conv_mfma<1><<<cgrid, 256, 0, stream>>>(nullptr, out1, wt2, sb1, out2, sums2);
    bnparam_kernel<<<1, 64, 0, stream>>>(sums2, g2, b2, sb2);

    finalize_kernel<<<dim3(HW2 / 32, NB), 256, 0, stream>>>(out2, x, sb2, out);
}

// Round 3
// 283.513 us; speedup vs baseline: 14.5455x; 1.1734x over previous
//
#include <hip/hip_runtime.h>

// B=32, C=64, H=W=112. Per-sample 3x3 convs via bf16 MFMA implicit GEMM.
// Per sample GEMM: M=64 (cout), K=576 (cin*9), N=12544 (pixels).
// Block: 28x16 pixel tile, 4 waves x 7 rows. Halo tile 30x18 in LDS.
#define HW    112
#define HW2   12544
#define CH    64
#define NB    32
#define TSX   16
#define RT    28            // rows per block
#define RW    7             // rows per wave
#define HP    18            // halo cols
#define HR    30            // halo rows
#define NPIX2 (HR*HP)       // 540 halo pixels
#define NPC   (NB*HW2)      // per-channel count for BN stats

using u16 = unsigned short;
typedef __attribute__((ext_vector_type(8))) short bf16x8;   // 8 bf16 = 4 VGPRs
typedef __attribute__((ext_vector_type(4))) float f32x4;

__device__ __forceinline__ float b2f(u16 u) {
    union { unsigned int i; float f; } c;
    c.i = ((unsigned int)u) << 16;
    return c.f;
}
__device__ __forceinline__ u16 f2b(float f) {
    union { float f; unsigned int i; } c;
    c.f = f;
    unsigned int x = c.i;
    x += 0x7fffu + ((x >> 16) & 1u);   // RNE
    return (u16)(x >> 16);
}

// LDS tile: [pix 0..539][ci 0..63] bf16, 128 B per pixel row.
// XOR-swizzle byte bits 4-6 with pix&7: conflict-free ds_read/write_b128.
__device__ __forceinline__ int swz(int pix, int ci) {
    return (pix * 128 + ci * 2) ^ ((pix & 7) << 4);
}

// MODE 0: input = raw f32 x [b][ci][y][x]   (conv1)
// MODE 1: input = bf16 out1 [b][y][x][ci] with BN1 affine + ReLU fused (conv2)
// wt: bf16 [b][tap][co][ci]. out: bf16 [b][y][x][co]. sums: 128 floats (sum,sumsq).
template<int MODE>
__global__ __launch_bounds__(256, 2)
void conv_mfma(const float* __restrict__ xf, const u16* __restrict__ xb,
               const u16* __restrict__ wt, const float* __restrict__ sbp,
               u16* __restrict__ out, float* __restrict__ sums)
{
    __shared__ u16 xt[NPIX2 * CH];
    // XCD swizzle: 896 blocks, 8 XCDs -> each XCD gets 112 consecutive ids
    // = 4 whole samples (weights + halo neighbors L2-local).
    const int bid = (int)blockIdx.x;
    const int sid = (bid & 7) * 112 + (bid >> 3);
    const int b   = sid / 28;
    const int rem = sid - b * 28;
    const int ty0 = (rem / 7) * RT, tx0 = (rem % 7) * TSX;
    const int tid = threadIdx.x;

    // ---- stage 30x18x64 input tile into LDS (pixel-major, swizzled) ----
    if (MODE == 0) {
        for (int task = tid; task < NPIX2 * 8; task += 256) {
            int g  = task / NPIX2;           // ci group (8 ci)
            int r  = task - g * NPIX2;       // pixel index in tile
            int iy = r / HP, ix = r - iy * HP;
            int gy = ty0 + iy - 1, gx = tx0 + ix - 1;
            bf16x8 pk = (bf16x8)0;
            if (((unsigned)gy < HW) && ((unsigned)gx < HW)) {
                const float* src = xf + ((size_t)b * CH + g * 8) * HW2 + gy * HW + gx;
#pragma unroll
                for (int j = 0; j < 8; ++j)
                    pk[j] = (short)f2b(src[(size_t)j * HW2]);
            }
            *(bf16x8*)((char*)xt + swz(r, g * 8)) = pk;
        }
    } else {
        // unit = (pixel, half); half = tid&1 is lane-constant -> sbp loads hoist
        for (int u = tid; u < NPIX2 * 2; u += 256) {
            int pix = u >> 1, half = (u & 1) * 32;
            int iy = pix / HP, ix = pix - iy * HP;
            int gy = ty0 + iy - 1, gx = tx0 + ix - 1;
            bool ok = ((unsigned)gy < HW) && ((unsigned)gx < HW);
            const u16* src = xb + ((size_t)b * HW2 + (size_t)gy * HW + gx) * CH + half;
#pragma unroll
            for (int j = 0; j < 4; ++j) {
                bf16x8 pk = (bf16x8)0;
                if (ok) {
                    bf16x8 v = *(const bf16x8*)(src + j * 8);
#pragma unroll
                    for (int e = 0; e < 8; ++e) {
                        int c = half + j * 8 + e;
                        float t = b2f((u16)v[e]) * sbp[c] + sbp[64 + c];
                        pk[e] = (short)f2b(t > 0.f ? t : 0.f);
                    }
                }
                *(bf16x8*)((char*)xt + swz(pix, half + j * 8)) = pk;
            }
        }
    }
    __syncthreads();

    // ---- MFMA main loop: wave = 7 pixel-rows x all 64 couts ----
    const int lane = tid & 63, wave = tid >> 6;
    const int px = lane & 15, kg = lane >> 4;
    const int y0 = wave * RW;
    const u16* wtb = wt + (size_t)b * 9 * CH * CH;

    f32x4 acc[RW][4];
#pragma unroll
    for (int r = 0; r < RW; ++r)
#pragma unroll
        for (int m = 0; m < 4; ++m) acc[r][m] = (f32x4)0.f;

#pragma unroll
    for (int dy = 0; dy < 3; ++dy)
#pragma unroll
    for (int dx = 0; dx < 3; ++dx)
#pragma unroll
    for (int kc = 0; kc < 2; ++kc) {
        const int ci0 = kc * 32 + kg * 8;
        const u16* wp = wtb + (size_t)(dy * 3 + dx) * CH * CH + ci0;
        bf16x8 af[4];
#pragma unroll
        for (int m = 0; m < 4; ++m)
            af[m] = *(const bf16x8*)(wp + (m * 16 + px) * CH);   // A: weights
#pragma unroll
        for (int r = 0; r < RW; ++r) {
            int pr = (y0 + r + dy) * HP + (px + dx);
            bf16x8 bfr = *(const bf16x8*)((const char*)xt + swz(pr, ci0)); // B: pixels
#pragma unroll
            for (int m = 0; m < 4; ++m)
                acc[r][m] = __builtin_amdgcn_mfma_f32_16x16x32_bf16(af[m], bfr, acc[r][m], 0, 0, 0);
        }
    }

    // ---- epilogue: bf16 store [b][y][x][co] + fused BN batch-stat partials ----
    float s[4][4], ss[4][4];
#pragma unroll
    for (int m = 0; m < 4; ++m)
#pragma unroll
        for (int q = 0; q < 4; ++q) { s[m][q] = 0.f; ss[m][q] = 0.f; }

    const size_t obase = ((size_t)b * HW2 + (size_t)(ty0 + y0) * HW + tx0 + px) * CH + kg * 4;
#pragma unroll
    for (int r = 0; r < RW; ++r) {
#pragma unroll
        for (int m = 0; m < 4; ++m) {
            float v0 = acc[r][m][0], v1 = acc[r][m][1], v2 = acc[r][m][2], v3 = acc[r][m][3];
            s[m][0] += v0; s[m][1] += v1; s[m][2] += v2; s[m][3] += v3;
            ss[m][0] += v0 * v0; ss[m][1] += v1 * v1; ss[m][2] += v2 * v2; ss[m][3] += v3 * v3;
            uint2 pk;
            pk.x = ((unsigned)f2b(v1) << 16) | f2b(v0);
            pk.y = ((unsigned)f2b(v3) << 16) | f2b(v2);
            *(uint2*)(out + obase + (size_t)r * HW * CH + m * 16) = pk;
        }
    }
    // reduce partials across the 16 px lanes
#pragma unroll
    for (int off = 1; off < 16; off <<= 1) {
#pragma unroll
        for (int m = 0; m < 4; ++m)
#pragma unroll
            for (int q = 0; q < 4; ++q) {
                s[m][q]  += __shfl_xor(s[m][q], off);
                ss[m][q] += __shfl_xor(ss[m][q], off);
            }
    }
    __syncthreads();                    // done reading xt; reuse as reduce buffer
    float* red = (float*)xt;
    if (px == 0) {
#pragma unroll
        for (int m = 0; m < 4; ++m)
#pragma unroll
            for (int q = 0; q < 4; ++q) {
                int c = m * 16 + kg * 4 + q;
                red[wave * 128 + c]      = s[m][q];
                red[wave * 128 + 64 + c] = ss[m][q];
            }
    }
    __syncthreads();
    if (tid < 128) {
        float t = red[tid] + red[128 + tid] + red[256 + tid] + red[384 + tid];
        atomicAdd(&sums[tid], t);
    }
}

// w [b][co][ci][3][3] f32  ->  wt [b][tap][co][ci] bf16
__global__ __launch_bounds__(256)
void repack_kernel(const float* __restrict__ w, u16* __restrict__ wt)
{
    int i  = blockIdx.x * 256 + threadIdx.x;   // 32*9*64*64 = 1179648 exact
    int ci = i & 63;
    int co = (i >> 6) & 63;
    int bt = i >> 12;                          // b*9 + t
    int t  = bt % 9;
    int b  = bt / 9;
    wt[i] = f2b(w[(((size_t)b * 64 + co) * 64 + ci) * 9 + t]);
}

__global__ void bnparam_kernel(const float* __restrict__ sums,
                               const float* __restrict__ gamma,
                               const float* __restrict__ beta,
                               float* __restrict__ sb)
{
    int c = threadIdx.x;
    if (c < 64) {
        float mean = sums[c] * (1.f / NPC);
        float var  = sums[64 + c] * (1.f / NPC) - mean * mean;
        float sc   = gamma[c] * rsqrtf(var + 1e-5f);
        sb[c]      = sc;
        sb[64 + c] = beta[c] - mean * sc;
    }
}

__global__ void zero_kernel(float* __restrict__ p, int n)
{
    int i = blockIdx.x * 256 + threadIdx.x;
    if (i < n) p[i] = 0.f;
}

// out = relu(bn2(y2) + x); y2 [b][pix][c] bf16, x/out [b][c][pix] f32 (LDS transpose)
__global__ __launch_bounds__(256)
void finalize_kernel(const u16* __restrict__ y2, const float* __restrict__ x,
                     const float* __restrict__ sb, float* __restrict__ out)
{
    __shared__ float lt[64][33];
    const int b  = blockIdx.y;
    const int p0 = blockIdx.x * 32;
    const int t  = threadIdx.x;
    {
        int pi = t >> 3, cg = (t & 7) * 8;
        const u16* src = y2 + ((size_t)b * HW2 + p0 + pi) * CH + cg;
        bf16x8 v = *(const bf16x8*)src;
#pragma unroll
        for (int j = 0; j < 8; ++j)
            lt[cg + j][pi] = b2f((u16)v[j]) * sb[cg + j] + sb[64 + cg + j];
    }
    __syncthreads();
    {
        int c = t >> 2, xg = (t & 3) * 8;
        size_t base = ((size_t)b * CH + c) * HW2 + p0 + xg;
        float4 x0 = *(const float4*)(x + base);
        float4 x1 = *(const float4*)(x + base + 4);
        float4 r0, r1;
        r0.x = fmaxf(lt[c][xg + 0] + x0.x, 0.f);
        r0.y = fmaxf(lt[c][xg + 1] + x0.y, 0.f);
        r0.z = fmaxf(lt[c][xg + 2] + x0.z, 0.f);
        r0.w = fmaxf(lt[c][xg + 3] + x0.w, 0.f);
        r1.x = fmaxf(lt[c][xg + 4] + x1.x, 0.f);
        r1.y = fmaxf(lt[c][xg + 5] + x1.y, 0.f);
        r1.z = fmaxf(lt[c][xg + 6] + x1.z, 0.f);
        r1.w = fmaxf(lt[c][xg + 7] + x1.w, 0.f);
        *(float4*)(out + base)     = r0;
        *(float4*)(out + base + 4) = r1;
    }
}

extern "C" void kernel_launch(void* const* d_in, const int* in_sizes, int n_in,
                              void* d_out, int out_size, void* d_ws, size_t ws_size,
                              hipStream_t stream)
{
    const float* x  = (const float*)d_in[0];
    const float* w1 = (const float*)d_in[1];
    const float* w2 = (const float*)d_in[2];
    const float* g1 = (const float*)d_in[3];
    const float* b1 = (const float*)d_in[4];
    const float* g2 = (const float*)d_in[5];
    const float* b2 = (const float*)d_in[6];
    float* out = (float*)d_out;

    char* ws = (char*)d_ws;
    const size_t nElem = (size_t)NB * CH * HW2;        // 25,690,112
    u16*   out1  = (u16*)ws;                           // [0, 51.38 MB)
    u16*   out2  = (u16*)(ws + nElem * 2);             // [51.38, 102.76 MB)
    float* st    = (float*)(ws + nElem * 4);           // 512 floats
    float* sums1 = st, *sums2 = st + 128, *sb1 = st + 256, *sb2 = st + 384;
    u16*   wt1   = out2;                               // dead until conv2 writes out2
    u16*   wt2   = (u16*)d_out;                        // dead until finalize writes out

    zero_kernel<<<1, 256, 0, stream>>>(st, 256);
    repack_kernel<<<4608, 256, 0, stream>>>(w1, wt1);

    const int cgrid = NB * 4 * 7;                      // 896 blocks
    conv_mfma<0><<<cgrid, 256, 0, stream>>>(x, nullptr, wt1, nullptr, out1, sums1);
    bnparam_kernel<<<1, 64, 0, stream>>>(sums1, g1, b1, sb1);

    repack_kernel<<<4608, 256, 0, stream>>>(w2, wt2);
    conv_mfma<1><<<cgrid, 256, 0, stream>>>(nullptr, out1, wt2, sb1, out2, sums2);
    bnparam_kernel<<<1, 64, 0, stream>>>(sums2, g2, b2, sb2);

    finalize_kernel<<<dim3(HW2 / 32, NB), 256, 0, stream>>>(out2, x, sb2, out);
}